// Round 1
// baseline (288.176 us; speedup 1.0000x reference)
//
#include <hip/hip_runtime.h>

#define NB 8
#define NC 4
#define NH 256
#define NW 256
#define HW (NH * NW)      // 65536
#define CHW (NC * HW)     // 262144
#define INFV 1e10f

// ---------------------------------------------------------------------------
// K1: softmax over channel axis (C=4). One thread per (b,h,w).
// ---------------------------------------------------------------------------
__global__ __launch_bounds__(256) void k_softmax(const float* __restrict__ pred,
                                                 float* __restrict__ p) {
    int idx = blockIdx.x * 256 + threadIdx.x;   // over B*HW = 524288
    int b  = idx >> 16;                         // HW == 65536
    int hw = idx & 65535;
    const float* src = pred + (size_t)b * CHW + hw;
    float x0 = src[0];
    float x1 = src[HW];
    float x2 = src[2 * HW];
    float x3 = src[3 * HW];
    float m  = fmaxf(fmaxf(x0, x1), fmaxf(x2, x3));
    float e0 = __expf(x0 - m);
    float e1 = __expf(x1 - m);
    float e2 = __expf(x2 - m);
    float e3 = __expf(x3 - m);
    float inv = 1.0f / (e0 + e1 + e2 + e3);
    float* dst = p + (size_t)b * CHW + hw;
    dst[0]      = e0 * inv;
    dst[HW]     = e1 * inv;
    dst[2 * HW] = e2 * inv;
    dst[3 * HW] = e3 * inv;
}

// ---------------------------------------------------------------------------
// K2: EDT pass 1 along W. One block per (b,h); thread i = output column.
// Computes, for each class c, min over seeds j (t[j]==c) of (i-j)^2,
// init 1e10 (matches reference exactly: seedless rows give exactly 1e10).
// ---------------------------------------------------------------------------
__global__ __launch_bounds__(256) void k_edt_w(const int* __restrict__ tgt,
                                               float* __restrict__ D) {
    int bh = blockIdx.x;            // b*NH + h
    int i  = threadIdx.x;
    __shared__ int t[NW];
    t[i] = tgt[(size_t)bh * NW + i];
    __syncthreads();

    float b0 = INFV, b1 = INFV, b2 = INFV, b3 = INFV;
    float diff = (float)i;          // i - j, j starts at 0
    #pragma unroll 4
    for (int j = 0; j < NW; ++j) {
        int   c = t[j];             // LDS broadcast (uniform addr) - free
        float d = diff * diff;      // exact: |diff| <= 255
        b0 = fminf(b0, c == 0 ? d : INFV);
        b1 = fminf(b1, c == 1 ? d : INFV);
        b2 = fminf(b2, c == 2 ? d : INFV);
        b3 = fminf(b3, c == 3 ? d : INFV);
        diff -= 1.0f;
    }
    int b = bh >> 8;
    int h = bh & 255;
    size_t o = (size_t)b * CHW + (size_t)h * NW + i;
    D[o]          = b0;
    D[o + HW]     = b1;
    D[o + 2 * HW] = b2;
    D[o + 3 * HW] = b3;
}

// ---------------------------------------------------------------------------
// K3: EDT pass 2 along H, in place, then sqrt. One block per (b,c,col);
// thread i = output row. Column staged in LDS (reads complete before the
// in-place writes, and blocks touch disjoint columns).
// ---------------------------------------------------------------------------
__global__ __launch_bounds__(256) void k_edt_h(float* __restrict__ D) {
    int blk = blockIdx.x;           // (b*NC + c)*NW + col
    int col = blk & 255;
    int bc  = blk >> 8;
    int i   = threadIdx.x;

    __shared__ float f[NH];
    size_t base = (size_t)bc * HW + (size_t)i * NW + col;
    f[i] = D[base];
    __syncthreads();

    float best = 3.4e38f;
    float diff = (float)i;
    #pragma unroll 8
    for (int j = 0; j < NH; ++j) {
        // finite candidates are exact ints <= 130050; fma == add for those
        best = fminf(best, __builtin_fmaf(diff, diff, f[j]));
        diff -= 1.0f;
    }
    D[base] = sqrtf(best);
}

// ---------------------------------------------------------------------------
// K4: fused boundary (|laplacian| of p, zero padding) * masked dist,
// reduce num/den. dist > 1e4 <=> empty channel (legit max ~360.6).
// ---------------------------------------------------------------------------
__global__ __launch_bounds__(256) void k_reduce(const float* __restrict__ p,
                                                const float* __restrict__ dist,
                                                double* __restrict__ acc) {
    int idx = blockIdx.x * 256 + threadIdx.x;   // over B*C*HW = 2097152
    int hw = idx & 65535;
    int h  = hw >> 8;
    int w  = hw & 255;
    size_t base = (size_t)idx;

    float c0 = p[base];
    float up = (h > 0)   ? p[base - NW] : 0.0f;
    float dn = (h < 255) ? p[base + NW] : 0.0f;
    float lf = (w > 0)   ? p[base - 1]  : 0.0f;
    float rt = (w < 255) ? p[base + 1]  : 0.0f;
    float lap = fabsf(up + dn + lf + rt - 4.0f * c0);

    float dv = dist[base];
    dv = (dv > 1e4f) ? 0.0f : dv;   // empty-channel mask

    float num = lap * dv;
    float den = lap;

    // wave (64-lane) reduction
    #pragma unroll
    for (int off = 32; off > 0; off >>= 1) {
        num += __shfl_down(num, off);
        den += __shfl_down(den, off);
    }
    __shared__ float sn[4], sd[4];
    int lane = threadIdx.x & 63;
    int wv   = threadIdx.x >> 6;
    if (lane == 0) { sn[wv] = num; sd[wv] = den; }
    __syncthreads();
    if (threadIdx.x == 0) {
        float n = sn[0] + sn[1] + sn[2] + sn[3];
        float d = sd[0] + sd[1] + sd[2] + sd[3];
        atomicAdd(&acc[0], (double)n);
        atomicAdd(&acc[1], (double)d);
    }
}

// ---------------------------------------------------------------------------
// K5: finalize scalar
// ---------------------------------------------------------------------------
__global__ void k_final(const double* __restrict__ acc, float* __restrict__ out) {
    out[0] = (float)(acc[0] / acc[1]);
}

extern "C" void kernel_launch(void* const* d_in, const int* in_sizes, int n_in,
                              void* d_out, int out_size, void* d_ws, size_t ws_size,
                              hipStream_t stream) {
    const float* pred = (const float*)d_in[0];
    const int*   tgt  = (const int*)d_in[1];
    float*       out  = (float*)d_out;

    float*  p   = (float*)d_ws;                 // B*C*H*W fp32 = 8 MB
    float*  D   = p + (size_t)NB * CHW;         // B*C*H*W fp32 = 8 MB
    double* acc = (double*)(D + (size_t)NB * CHW);

    hipMemsetAsync(acc, 0, 2 * sizeof(double), stream);

    k_softmax<<<(NB * HW) / 256, 256, 0, stream>>>(pred, p);
    k_edt_w  <<<NB * NH,         256, 0, stream>>>(tgt, D);
    k_edt_h  <<<NB * NC * NW,    256, 0, stream>>>(D);
    k_reduce <<<(NB * CHW) / 256,256, 0, stream>>>(p, D, acc);
    k_final  <<<1, 1,                 0, stream>>>(acc, out);
}

// Round 2
// 60.753 us; speedup vs baseline: 4.7434x; 4.7434x over previous
//
#include <hip/hip_runtime.h>

#define NB 8
#define NC 4
#define NH 256
#define NW 256
#define HW (NH * NW)      // 65536
#define CHW (NC * HW)     // 262144
#define INFV 1e10f
#define RED_BLOCKS 1024

// ---------------------------------------------------------------------------
// K1: softmax over channel axis (C=4). One thread per (b,h,w).
// ---------------------------------------------------------------------------
__global__ __launch_bounds__(256) void k_softmax(const float* __restrict__ pred,
                                                 float* __restrict__ p) {
    int idx = blockIdx.x * 256 + threadIdx.x;   // over B*HW = 524288
    int b  = idx >> 16;                         // HW == 65536
    int hw = idx & 65535;
    const float* src = pred + (size_t)b * CHW + hw;
    float x0 = src[0];
    float x1 = src[HW];
    float x2 = src[2 * HW];
    float x3 = src[3 * HW];
    float m  = fmaxf(fmaxf(x0, x1), fmaxf(x2, x3));
    float e0 = __expf(x0 - m);
    float e1 = __expf(x1 - m);
    float e2 = __expf(x2 - m);
    float e3 = __expf(x3 - m);
    float inv = 1.0f / (e0 + e1 + e2 + e3);
    float* dst = p + (size_t)b * CHW + hw;
    dst[0]      = e0 * inv;
    dst[HW]     = e1 * inv;
    dst[2 * HW] = e2 * inv;
    dst[3 * HW] = e3 * inv;
}

// ---------------------------------------------------------------------------
// K2: EDT pass 1 along W — ballot version. One block (256 thr) per (b,h).
// Row is binary per class: nearest-seed distance found from 256-bit seed
// masks (4x uint64) via clz/ffs. Exact: d^2 with d<=255, INFV if class
// absent from row (matches reference bit-for-bit).
// ---------------------------------------------------------------------------
__global__ __launch_bounds__(256) void k_edt_w(const int* __restrict__ tgt,
                                               float* __restrict__ D) {
    int bh = blockIdx.x;            // b*NH + h
    int i  = threadIdx.x;
    int wv = i >> 6;                // wave id (0..3)
    int ln = i & 63;

    int tv = tgt[(size_t)bh * NW + i];

    __shared__ unsigned long long mk[NC][4];
    #pragma unroll
    for (int c = 0; c < NC; ++c) {
        unsigned long long m = __ballot(tv == c);
        if (ln == 0) mk[c][wv] = m;
    }
    __syncthreads();

    unsigned long long le = (ln == 63) ? ~0ull : ((1ull << (ln + 1)) - 1ull);
    unsigned long long ge = ~0ull << ln;

    float res[NC];
    #pragma unroll
    for (int c = 0; c < NC; ++c) {
        // nearest set bit j <= i  (scan words ascending, keep last nonzero)
        int jl = -1000;
        #pragma unroll
        for (int k = 0; k < 4; ++k) {
            unsigned long long x = mk[c][k];
            x = (k > wv) ? 0ull : ((k == wv) ? (x & le) : x);
            if (x) jl = k * 64 + 63 - __clzll((long long)x);
        }
        // nearest set bit j >= i  (scan words descending, keep last nonzero)
        int jr = 1000;
        #pragma unroll
        for (int k = 3; k >= 0; --k) {
            unsigned long long x = mk[c][k];
            x = (k < wv) ? 0ull : ((k == wv) ? (x & ge) : x);
            if (x) jr = k * 64 + __ffsll((unsigned long long)x) - 1;
        }
        int dl = i - jl;
        int dr = jr - i;
        int dd = min(dl, dr);
        res[c] = (dd > 255) ? INFV : (float)(dd * dd);
    }

    int b = bh >> 8;
    int h = bh & 255;
    size_t o = (size_t)b * CHW + (size_t)h * NW + i;
    D[o]          = res[0];
    D[o + HW]     = res[1];
    D[o + 2 * HW] = res[2];
    D[o + 3 * HW] = res[3];
}

// ---------------------------------------------------------------------------
// K3: EDT pass 2 along H, in place, then sqrt. One block per (b,c,col);
// thread i = output row. Column staged in LDS; j-loop unrolled x4 with
// float4 (ds_read_b128, uniform-addr broadcast).
// ---------------------------------------------------------------------------
__global__ __launch_bounds__(256) void k_edt_h(float* __restrict__ D) {
    int blk = blockIdx.x;           // (b*NC + c)*NW + col
    int col = blk & 255;
    int bc  = blk >> 8;
    int i   = threadIdx.x;

    __shared__ __align__(16) float f[NH];
    size_t base = (size_t)bc * HW + (size_t)i * NW + col;
    f[i] = D[base];
    __syncthreads();

    float best = 3.4e38f;
    float diff = (float)i;
    #pragma unroll 4
    for (int j = 0; j < NH; j += 4) {
        float4 q = *(const float4*)&f[j];
        // diff*diff exact (ints <= 65025) -> fma == reference's add
        best = fminf(best, __builtin_fmaf(diff, diff, q.x)); diff -= 1.0f;
        best = fminf(best, __builtin_fmaf(diff, diff, q.y)); diff -= 1.0f;
        best = fminf(best, __builtin_fmaf(diff, diff, q.z)); diff -= 1.0f;
        best = fminf(best, __builtin_fmaf(diff, diff, q.w)); diff -= 1.0f;
    }
    D[base] = sqrtf(best);
}

// ---------------------------------------------------------------------------
// K4: fused boundary (|laplacian| of p, zero padding) * masked dist,
// per-block partial sums (NO contended atomics).
// ---------------------------------------------------------------------------
__global__ __launch_bounds__(256) void k_reduce(const float* __restrict__ p,
                                                const float* __restrict__ dist,
                                                float2* __restrict__ partial) {
    float num = 0.0f, den = 0.0f;
    for (int idx = blockIdx.x * 256 + threadIdx.x; idx < NB * CHW;
         idx += RED_BLOCKS * 256) {
        int hw = idx & 65535;
        int h  = hw >> 8;
        int w  = hw & 255;
        size_t base = (size_t)idx;

        float c0 = p[base];
        float up = (h > 0)   ? p[base - NW] : 0.0f;
        float dn = (h < 255) ? p[base + NW] : 0.0f;
        float lf = (w > 0)   ? p[base - 1]  : 0.0f;
        float rt = (w < 255) ? p[base + 1]  : 0.0f;
        float lap = fabsf(up + dn + lf + rt - 4.0f * c0);

        float dv = dist[base];
        dv = (dv > 1e4f) ? 0.0f : dv;   // empty-channel mask

        num += lap * dv;
        den += lap;
    }

    #pragma unroll
    for (int off = 32; off > 0; off >>= 1) {
        num += __shfl_down(num, off);
        den += __shfl_down(den, off);
    }
    __shared__ float sn[4], sd[4];
    int lane = threadIdx.x & 63;
    int wv   = threadIdx.x >> 6;
    if (lane == 0) { sn[wv] = num; sd[wv] = den; }
    __syncthreads();
    if (threadIdx.x == 0) {
        partial[blockIdx.x] = make_float2(sn[0] + sn[1] + sn[2] + sn[3],
                                          sd[0] + sd[1] + sd[2] + sd[3]);
    }
}

// ---------------------------------------------------------------------------
// K5: final reduction of 1024 partials + divide. One block.
// ---------------------------------------------------------------------------
__global__ __launch_bounds__(256) void k_final(const float2* __restrict__ partial,
                                               float* __restrict__ out) {
    double n = 0.0, d = 0.0;
    for (int i = threadIdx.x; i < RED_BLOCKS; i += 256) {
        float2 v = partial[i];
        n += (double)v.x;
        d += (double)v.y;
    }
    #pragma unroll
    for (int off = 32; off > 0; off >>= 1) {
        n += __shfl_down(n, off);
        d += __shfl_down(d, off);
    }
    __shared__ double snd[4], sdd[4];
    int lane = threadIdx.x & 63;
    int wv   = threadIdx.x >> 6;
    if (lane == 0) { snd[wv] = n; sdd[wv] = d; }
    __syncthreads();
    if (threadIdx.x == 0) {
        double nn = snd[0] + snd[1] + snd[2] + snd[3];
        double dd = sdd[0] + sdd[1] + sdd[2] + sdd[3];
        out[0] = (float)(nn / dd);
    }
}

extern "C" void kernel_launch(void* const* d_in, const int* in_sizes, int n_in,
                              void* d_out, int out_size, void* d_ws, size_t ws_size,
                              hipStream_t stream) {
    const float* pred = (const float*)d_in[0];
    const int*   tgt  = (const int*)d_in[1];
    float*       out  = (float*)d_out;

    float*  p       = (float*)d_ws;                 // 8 MB
    float*  D       = p + (size_t)NB * CHW;         // 8 MB
    float2* partial = (float2*)(D + (size_t)NB * CHW); // 8 KB

    k_softmax<<<(NB * HW) / 256,  256, 0, stream>>>(pred, p);
    k_edt_w  <<<NB * NH,          256, 0, stream>>>(tgt, D);
    k_edt_h  <<<NB * NC * NW,     256, 0, stream>>>(D);
    k_reduce <<<RED_BLOCKS,       256, 0, stream>>>(p, D, partial);
    k_final  <<<1,                256, 0, stream>>>(partial, out);
}

// Round 3
// 37.683 us; speedup vs baseline: 7.6474x; 1.6122x over previous
//
#include <hip/hip_runtime.h>

#define NB 8
#define NC 4
#define NH 256
#define NW 256
#define HW (NH * NW)      // 65536
#define CHW (NC * HW)     // 262144
#define INFV 1e10f
#define MAIN_BLOCKS ((NB * HW) / 256)   // 2048

// ---------------------------------------------------------------------------
// K1: EDT pass 1 along W — ballot version. One block (256 thr) per (b,h).
// Exact: d^2 with d<=255, INFV if class absent from row.
// ---------------------------------------------------------------------------
__global__ __launch_bounds__(256) void k_edt_w(const int* __restrict__ tgt,
                                               float* __restrict__ D) {
    int bh = blockIdx.x;            // b*NH + h
    int i  = threadIdx.x;
    int wv = i >> 6;                // wave id (0..3)
    int ln = i & 63;

    int tv = tgt[(size_t)bh * NW + i];

    __shared__ unsigned long long mk[NC][4];
    #pragma unroll
    for (int c = 0; c < NC; ++c) {
        unsigned long long m = __ballot(tv == c);
        if (ln == 0) mk[c][wv] = m;
    }
    __syncthreads();

    unsigned long long le = (ln == 63) ? ~0ull : ((1ull << (ln + 1)) - 1ull);
    unsigned long long ge = ~0ull << ln;

    float res[NC];
    #pragma unroll
    for (int c = 0; c < NC; ++c) {
        int jl = -1000;
        #pragma unroll
        for (int k = 0; k < 4; ++k) {
            unsigned long long x = mk[c][k];
            x = (k > wv) ? 0ull : ((k == wv) ? (x & le) : x);
            if (x) jl = k * 64 + 63 - __clzll((long long)x);
        }
        int jr = 1000;
        #pragma unroll
        for (int k = 3; k >= 0; --k) {
            unsigned long long x = mk[c][k];
            x = (k < wv) ? 0ull : ((k == wv) ? (x & ge) : x);
            if (x) jr = k * 64 + __ffsll((unsigned long long)x) - 1;
        }
        int dl = i - jl;
        int dr = jr - i;
        int dd = min(dl, dr);
        res[c] = (dd > 255) ? INFV : (float)(dd * dd);
    }

    int b = bh >> 8;
    int h = bh & 255;
    size_t o = (size_t)b * CHW + (size_t)h * NW + i;
    D[o]          = res[0];
    D[o + HW]     = res[1];
    D[o + 2 * HW] = res[2];
    D[o + 3 * HW] = res[3];
}

// ---------------------------------------------------------------------------
// softmax of the 4 channel logits at pixel offset hw of batch-base pred_b.
// ---------------------------------------------------------------------------
__device__ __forceinline__ void softmax4(const float* __restrict__ pred_b,
                                         int hw, float o[NC]) {
    float x0 = pred_b[hw];
    float x1 = pred_b[hw + HW];
    float x2 = pred_b[hw + 2 * HW];
    float x3 = pred_b[hw + 3 * HW];
    float m  = fmaxf(fmaxf(x0, x1), fmaxf(x2, x3));
    float e0 = __expf(x0 - m);
    float e1 = __expf(x1 - m);
    float e2 = __expf(x2 - m);
    float e3 = __expf(x3 - m);
    float inv = 1.0f / (e0 + e1 + e2 + e3);
    o[0] = e0 * inv; o[1] = e1 * inv; o[2] = e2 * inv; o[3] = e3 * inv;
}

// ---------------------------------------------------------------------------
// K2: fused EDT pass-2 (early-exit radial scan, exact) + softmax stencil
// boundary + masked-dist reduction. One thread per (b,h,w).
// ---------------------------------------------------------------------------
__global__ __launch_bounds__(256) void k_main(const float* __restrict__ pred,
                                              const float* __restrict__ D,
                                              float2* __restrict__ partial) {
    int idx = blockIdx.x * 256 + threadIdx.x;   // over B*HW
    int b  = idx >> 16;
    int hw = idx & 65535;
    int h  = hw >> 8;
    int w  = hw & 255;

    const float* pred_b = pred + (size_t)b * CHW;

    // softmax at the 5 stencil points (zero prob outside image = zero pad)
    float pc[NC], pu[NC] = {0,0,0,0}, pd[NC] = {0,0,0,0},
          pl[NC] = {0,0,0,0}, pr[NC] = {0,0,0,0};
    softmax4(pred_b, hw, pc);
    if (h > 0)   softmax4(pred_b, hw - NW, pu);
    if (h < 255) softmax4(pred_b, hw + NW, pd);
    if (w > 0)   softmax4(pred_b, hw - 1,  pl);
    if (w < 255) softmax4(pred_b, hw + 1,  pr);

    float num = 0.0f, den = 0.0f;
    #pragma unroll
    for (int c = 0; c < NC; ++c) {
        float lap = fabsf(pu[c] + pd[c] + pl[c] + pr[c] - 4.0f * pc[c]);

        // exact column min: min_j (h-j)^2 + f[j], early exit when r^2 >= best
        const float* f = D + (size_t)b * CHW + (size_t)c * HW + w;
        float best = f[(size_t)h * NW];               // r = 0
        for (int r = 1; r < NH; ++r) {
            float rr = (float)(r * r);                // exact int <= 65025
            if (rr >= best) break;
            int huu = h - r, hdd = h + r;
            if (huu >= 0)  best = fminf(best, rr + f[(size_t)huu * NW]);
            if (hdd < NH)  best = fminf(best, rr + f[(size_t)hdd * NW]);
        }
        float dv = (best > 1e8f) ? 0.0f : sqrtf(best); // empty-channel mask

        num += lap * dv;
        den += lap;
    }

    #pragma unroll
    for (int off = 32; off > 0; off >>= 1) {
        num += __shfl_down(num, off);
        den += __shfl_down(den, off);
    }
    __shared__ float sn[4], sd[4];
    int lane = threadIdx.x & 63;
    int wv   = threadIdx.x >> 6;
    if (lane == 0) { sn[wv] = num; sd[wv] = den; }
    __syncthreads();
    if (threadIdx.x == 0) {
        partial[blockIdx.x] = make_float2(sn[0] + sn[1] + sn[2] + sn[3],
                                          sd[0] + sd[1] + sd[2] + sd[3]);
    }
}

// ---------------------------------------------------------------------------
// K3: final reduction of partials + divide. One block.
// ---------------------------------------------------------------------------
__global__ __launch_bounds__(256) void k_final(const float2* __restrict__ partial,
                                               float* __restrict__ out) {
    double n = 0.0, d = 0.0;
    for (int i = threadIdx.x; i < MAIN_BLOCKS; i += 256) {
        float2 v = partial[i];
        n += (double)v.x;
        d += (double)v.y;
    }
    #pragma unroll
    for (int off = 32; off > 0; off >>= 1) {
        n += __shfl_down(n, off);
        d += __shfl_down(d, off);
    }
    __shared__ double snd[4], sdd[4];
    int lane = threadIdx.x & 63;
    int wv   = threadIdx.x >> 6;
    if (lane == 0) { snd[wv] = n; sdd[wv] = d; }
    __syncthreads();
    if (threadIdx.x == 0) {
        double nn = snd[0] + snd[1] + snd[2] + snd[3];
        double dd = sdd[0] + sdd[1] + sdd[2] + sdd[3];
        out[0] = (float)(nn / dd);
    }
}

extern "C" void kernel_launch(void* const* d_in, const int* in_sizes, int n_in,
                              void* d_out, int out_size, void* d_ws, size_t ws_size,
                              hipStream_t stream) {
    const float* pred = (const float*)d_in[0];
    const int*   tgt  = (const int*)d_in[1];
    float*       out  = (float*)d_out;

    float*  D       = (float*)d_ws;                     // 8 MB
    float2* partial = (float2*)(D + (size_t)NB * CHW);  // 16 KB

    k_edt_w<<<NB * NH,     256, 0, stream>>>(tgt, D);
    k_main <<<MAIN_BLOCKS, 256, 0, stream>>>(pred, D, partial);
    k_final<<<1,           256, 0, stream>>>(partial, out);
}